// Round 3
// baseline (189.376 us; speedup 1.0000x reference)
//
#include <hip/hip_runtime.h>

#define D_MODEL 1024
#define SEQ 2048
#define BATCH 4
#define HEADS 16
#define HDIM 64

typedef short bf16x8 __attribute__((ext_vector_type(8)));
typedef float f32x4 __attribute__((ext_vector_type(4)));

#define FENCE() asm volatile("" ::: "memory")

__device__ __forceinline__ unsigned short f2bf(float f) {
  union { float f; unsigned int u; } c; c.f = f;
  unsigned int u = c.u;
  unsigned int r = (u + 0x7FFFu + ((u >> 16) & 1u)) >> 16;
  return (unsigned short)r;
}

__device__ __forceinline__ unsigned int cvt_pk_bf16(float a, float b) {
  unsigned int r;
  asm("v_cvt_pk_bf16_f32 %0, %1, %2" : "=v"(r) : "v"(a), "v"(b));
  return r;
}

__device__ __forceinline__ void async16(const void* g, const void* lds) {
  __builtin_amdgcn_global_load_lds((const __attribute__((address_space(1))) void*)g,
                                   (__attribute__((address_space(3))) void*)lds, 16, 0, 0);
}

// ---------------------------------------------------------------- converts
__global__ void cvt_kernel(const float* __restrict__ src,
                           unsigned short* __restrict__ dst, int n4) {
  int i = blockIdx.x * 256 + threadIdx.x;
  if (i >= n4) return;
  float4 v = ((const float4*)src)[i];
  ushort4 o;
  o.x = f2bf(v.x); o.y = f2bf(v.y); o.z = f2bf(v.z); o.w = f2bf(v.w);
  ((ushort4*)dst)[i] = o;
}

__global__ void cvtw_kernel(const float* __restrict__ Wq, const float* __restrict__ Wk,
                            const float* __restrict__ Wv, const float* __restrict__ Wo,
                            unsigned short* __restrict__ Wqkv,
                            unsigned short* __restrict__ Wob) {
  int b = blockIdx.x >> 10;   // 0..3
  int i = (blockIdx.x & 1023) * 256 + threadIdx.x;
  const float* s = (b == 0) ? Wq : (b == 1) ? Wk : (b == 2) ? Wv : Wo;
  unsigned short* d = (b == 3) ? Wob : (Wqkv + b * (D_MODEL * D_MODEL));
  float4 v = ((const float4*)s)[i];
  ushort4 o;
  o.x = f2bf(v.x); o.y = f2bf(v.y); o.z = f2bf(v.z); o.w = f2bf(v.w);
  ((ushort4*)d)[i] = o;
}

// ---------------------------------------------------------------- GEMM  C = A * B^T
// 2-phase counted-vmcnt pipeline: LDS double-buffer, loads issued 2 tiles ahead,
// raw s_barrier (no implicit vmcnt(0) drain), setprio around the MFMA cluster.
// MODE 0: N in [0,2048) of Wqkv -> scatter bf16 to Q/K [B*H][S][Dh]
// MODE 1: N=1024 (Wo) -> fp32 out [M][1024]
// MODE 2: N in [2048,3072) (Wv) -> SWAPPED mfma, scatter V^T [B*H][Dh][S]
template <int MODE>
__global__ __launch_bounds__(256, 2) void gemm_bt(
    const unsigned short* __restrict__ A, const unsigned short* __restrict__ Bw,
    unsigned short* __restrict__ Qd, unsigned short* __restrict__ Kd,
    unsigned short* __restrict__ Vtd, float* __restrict__ Od) {
  __shared__ unsigned short At[2][128 * 32];
  __shared__ unsigned short Bt[2][128 * 32];
  const int t = threadIdx.x;
  const int lane = t & 63;
  const int wid = t >> 6;
  const int wr = wid >> 1;
  const int wc = wid & 1;
  const int m0 = blockIdx.y * 128;
  const int n0 = (MODE == 2 ? 2048 : 0) + blockIdx.x * 128;
  const int K = 1024;
  f32x4 acc[4][4] = {};

  const int srow = t >> 2;          // 0..63
  const int skk = (t & 3) << 3;     // 0,8,16,24
  const unsigned short* Ap = A + (size_t)(m0 + srow) * K + skk;
  const unsigned short* Bp = Bw + (size_t)(n0 + srow) * K + skk;
  const int lrow = lane & 15;
  const int lk = (lane >> 4) << 3;

#define STAGE_G(kt, buf)                                  \
  do {                                                    \
    async16(Ap + (kt), &At[buf][t * 8]);                  \
    async16(Ap + (kt) + 64 * K, &At[buf][2048 + t * 8]);  \
    async16(Bp + (kt), &Bt[buf][t * 8]);                  \
    async16(Bp + (kt) + 64 * K, &Bt[buf][2048 + t * 8]);  \
  } while (0)

  STAGE_G(0, 0);
  STAGE_G(32, 1);

  for (int kt = 0; kt < K; kt += 32) {
    const int buf = (kt >> 5) & 1;
    if (kt + 32 < K) asm volatile("s_waitcnt vmcnt(4)" ::: "memory");
    else             asm volatile("s_waitcnt vmcnt(0)" ::: "memory");
    __builtin_amdgcn_s_barrier();
    FENCE();
    bf16x8 af[4], bfr[4];
#pragma unroll
    for (int f = 0; f < 4; ++f) {
      af[f] = *(const bf16x8*)&At[buf][(wr * 64 + f * 16 + lrow) * 32 + lk];
      bfr[f] = *(const bf16x8*)&Bt[buf][(wc * 64 + f * 16 + lrow) * 32 + lk];
    }
    __builtin_amdgcn_s_setprio(1);
#pragma unroll
    for (int fm = 0; fm < 4; ++fm)
#pragma unroll
      for (int fn = 0; fn < 4; ++fn) {
        if (MODE == 2)
          acc[fm][fn] = __builtin_amdgcn_mfma_f32_16x16x32_bf16(bfr[fn], af[fm],
                                                                acc[fm][fn], 0, 0, 0);
        else
          acc[fm][fn] = __builtin_amdgcn_mfma_f32_16x16x32_bf16(af[fm], bfr[fn],
                                                                acc[fm][fn], 0, 0, 0);
      }
    __builtin_amdgcn_s_setprio(0);
    FENCE();
    __builtin_amdgcn_s_barrier();
    FENCE();
    if (kt + 64 < K) STAGE_G(kt + 64, buf);
  }
#undef STAGE_G

#pragma unroll
  for (int fm = 0; fm < 4; ++fm) {
#pragma unroll
    for (int fn = 0; fn < 4; ++fn) {
#pragma unroll
      for (int r = 0; r < 4; ++r) {
        float v = acc[fm][fn][r];
        if (MODE == 2) {
          // C^T layout: row = n-sub, col = m
          int n = n0 + wc * 64 + fn * 16 + (lane >> 4) * 4 + r;
          int m = m0 + wr * 64 + fm * 16 + (lane & 15);
          int h = (n >> 6) & 15;
          int d = n & 63;
          int b = m >> 11;
          int s = m & 2047;
          Vtd[(((size_t)(b * HEADS + h)) * HDIM + d) * SEQ + s] = f2bf(v);
        } else {
          int m = m0 + wr * 64 + fm * 16 + (lane >> 4) * 4 + r;
          int n = n0 + wc * 64 + fn * 16 + (lane & 15);
          if (MODE == 0) {
            int p = n >> 10;  // 0=Q, 1=K
            int h = (n >> 6) & 15;
            int dh = n & 63;
            int b = m >> 11;
            int s = m & 2047;
            unsigned short* dst = (p == 0) ? Qd : Kd;
            dst[(((size_t)(b * HEADS + h)) * SEQ + s) * HDIM + dh] = f2bf(v);
          } else {
            Od[(size_t)m * D_MODEL + n] = v;
          }
        }
      }
    }
  }
}

// ---------------------------------------------------------------- flash attention (causal)
// Q,K: [B*H][S][Dh] bf16.  Vt: [B*H][Dh][S] bf16.  Out ctx: [B*S][D_MODEL] bf16.
// Double-buffered K/V staging with counted vmcnt; swapped QK^T; in-register
// softmax with exact defer-rescale (skip when tile max <= running max);
// packed-b32 P via LDS; XOR-swizzled K/V tiles; setprio around MFMA clusters.
__global__ __launch_bounds__(256, 3) void attn_fwd(
    const unsigned short* __restrict__ Qg, const unsigned short* __restrict__ Kg,
    const unsigned short* __restrict__ Vtg, unsigned short* __restrict__ Cg) {
  __shared__ unsigned short Kl[2][64 * 64];   // [key][dh], rows XOR-swizzled
  __shared__ unsigned short Vl[2][64 * 64];   // [dh][key], rows XOR-swizzled
  __shared__ unsigned short Pl[4][32 * 72];   // per-wave P [q][key] +8 pad

  const int t = threadIdx.x;
  const int lane = t & 63;
  const int wq = t >> 6;
  const int bh = blockIdx.x;
  const int q0 = (15 - blockIdx.y) * 128;  // heavy blocks first
  const size_t base = (size_t)bh * SEQ * HDIM;
  const unsigned short* Qb = Qg + base;
  const unsigned short* Kb = Kg + base;
  const unsigned short* Vb = Vtg + base;  // [Dh][S]
  char* PlB = (char*)&Pl[wq][0];

  const int l15 = lane & 15;
  const int lh = lane >> 4;  // 0..3
  const int qrow = q0 + wq * 32;

  bf16x8 qf[2][2];
#pragma unroll
  for (int fm = 0; fm < 2; ++fm)
#pragma unroll
    for (int ks = 0; ks < 2; ++ks)
      qf[fm][ks] = *(const bf16x8*)&Qb[(size_t)(qrow + fm * 16 + l15) * HDIM +
                                       ks * 32 + lh * 8];

  f32x4 acc[2][4] = {};
  float mrun[2] = {-1e30f, -1e30f};
  float lrun[2] = {0.f, 0.f};

  // staging: dest byte p = t*16 (+4096). row = p>>7, stored col = (col ^ ((row&7)<<4))
  const int srow = t >> 3;                         // 0..31
  const int sc8 = ((t & 7) ^ (srow & 7)) << 3;     // element offset within row

#define STAGE_KV(kv, buf)                                                  \
  do {                                                                     \
    async16(Kb + (size_t)((kv) + srow) * HDIM + sc8, &Kl[buf][t * 8]);     \
    async16(Kb + (size_t)((kv) + 32 + srow) * HDIM + sc8,                  \
            &Kl[buf][2048 + t * 8]);                                       \
    async16(Vb + (size_t)srow * SEQ + (kv) + sc8, &Vl[buf][t * 8]);        \
    async16(Vb + (size_t)(32 + srow) * SEQ + (kv) + sc8,                   \
            &Vl[buf][2048 + t * 8]);                                       \
  } while (0)

  STAGE_KV(0, 0);

  const int kv_end = q0 + 128;
  for (int kv0 = 0; kv0 < kv_end; kv0 += 64) {
    const int buf = (kv0 >> 6) & 1;
    if (kv0 + 64 < kv_end) {
      STAGE_KV(kv0 + 64, buf ^ 1);
      asm volatile("s_waitcnt vmcnt(4)" ::: "memory");
    } else {
      asm volatile("s_waitcnt vmcnt(0)" ::: "memory");
    }
    __builtin_amdgcn_s_barrier();
    FENCE();

    if (kv0 <= qrow + 31) {
      const char* KlB = (const char*)&Kl[buf][0];
      const char* VlB = (const char*)&Vl[buf][0];

      // ---- S^T = K Q^T : C[key][q], lane holds 16 keys for q = l15
      f32x4 sfr[2][4] = {};
      __builtin_amdgcn_s_setprio(1);
#pragma unroll
      for (int ks = 0; ks < 2; ++ks) {
        bf16x8 kf[4];
#pragma unroll
        for (int fn = 0; fn < 4; ++fn) {
          int row = fn * 16 + l15;
          kf[fn] = *(const bf16x8*)&KlB[row * 128 +
                                        ((ks * 64 + lh * 16) ^ ((row & 7) << 4))];
        }
#pragma unroll
        for (int fm = 0; fm < 2; ++fm)
#pragma unroll
          for (int fn = 0; fn < 4; ++fn)
            sfr[fm][fn] = __builtin_amdgcn_mfma_f32_16x16x32_bf16(
                kf[fn], qf[fm][ks], sfr[fm][fn], 0, 0, 0);
      }
      __builtin_amdgcn_s_setprio(0);

      const bool need_mask = (kv0 + 63) > qrow;
#pragma unroll
      for (int fm = 0; fm < 2; ++fm) {
        const int q = qrow + fm * 16 + l15;
        float p[4][4];
        float mt = -1e30f;
#pragma unroll
        for (int fn = 0; fn < 4; ++fn)
#pragma unroll
          for (int r = 0; r < 4; ++r) {
            float v = sfr[fm][fn][r] * 0.125f;
            if (need_mask) {
              int key = kv0 + fn * 16 + lh * 4 + r;
              v = (key <= q) ? v : -1e30f;
            }
            p[fn][r] = v;
            mt = fmaxf(mt, v);
          }
        mt = fmaxf(mt, __shfl_xor(mt, 16));
        mt = fmaxf(mt, __shfl_xor(mt, 32));
        const bool upd = !__all(mt <= mrun[fm]);  // wave-uniform; exact (THR=0)
        float mnew = mrun[fm];
        float c = 1.0f;
        if (upd) {
          mnew = fmaxf(mrun[fm], mt);
          c = __expf(mrun[fm] - mnew);
          mrun[fm] = mnew;
        }
        float st = 0.f;
#pragma unroll
        for (int fn = 0; fn < 4; ++fn)
#pragma unroll
          for (int r = 0; r < 4; ++r) {
            p[fn][r] = __expf(p[fn][r] - mnew);
            st += p[fn][r];
          }
        st += __shfl_xor(st, 16);
        st += __shfl_xor(st, 32);
        if (upd) {
          lrun[fm] = lrun[fm] * c + st;
          float cr[4];
#pragma unroll
          for (int r = 0; r < 4; ++r) cr[r] = __shfl(c, lh * 4 + r);
#pragma unroll
          for (int fn = 0; fn < 4; ++fn)
#pragma unroll
            for (int r = 0; r < 4; ++r) acc[fm][fn][r] *= cr[r];
        } else {
          lrun[fm] += st;
        }

        // packed P writes: [q=fm*16+l15][key], b32 (2 keys) each
#pragma unroll
        for (int fn = 0; fn < 4; ++fn) {
#pragma unroll
          for (int w = 0; w < 2; ++w) {
            unsigned int pk = cvt_pk_bf16(p[fn][2 * w], p[fn][2 * w + 1]);
            *(unsigned int*)&PlB[(fm * 16 + l15) * 144 + fn * 32 + lh * 8 + w * 4] = pk;
          }
        }
      }

      // ---- ctx += P V
      __builtin_amdgcn_s_setprio(1);
#pragma unroll
      for (int ks = 0; ks < 2; ++ks) {
        bf16x8 pf[2], vf[4];
#pragma unroll
        for (int fm = 0; fm < 2; ++fm)
          pf[fm] = *(const bf16x8*)&PlB[(fm * 16 + l15) * 144 + ks * 64 + lh * 16];
#pragma unroll
        for (int fn = 0; fn < 4; ++fn) {
          int row = fn * 16 + l15;
          vf[fn] = *(const bf16x8*)&VlB[row * 128 +
                                        ((ks * 64 + lh * 16) ^ ((row & 7) << 4))];
        }
#pragma unroll
        for (int fm = 0; fm < 2; ++fm)
#pragma unroll
          for (int fn = 0; fn < 4; ++fn)
            acc[fm][fn] = __builtin_amdgcn_mfma_f32_16x16x32_bf16(
                pf[fm], vf[fn], acc[fm][fn], 0, 0, 0);
      }
      __builtin_amdgcn_s_setprio(0);
    }
    FENCE();
    __builtin_amdgcn_s_barrier();
    FENCE();
  }
#undef STAGE_KV

  const int b = bh >> 4;
  const int h = bh & 15;
#pragma unroll
  for (int fm = 0; fm < 2; ++fm) {
    float inv = 1.0f / lrun[fm];
    float ivr[4];
#pragma unroll
    for (int r = 0; r < 4; ++r) ivr[r] = __shfl(inv, lh * 4 + r);
#pragma unroll
    for (int r = 0; r < 4; ++r) {
      int s = qrow + fm * 16 + lh * 4 + r;
#pragma unroll
      for (int fn = 0; fn < 4; ++fn) {
        int dh = fn * 16 + l15;
        Cg[((size_t)(b * SEQ + s)) * D_MODEL + h * HDIM + dh] =
            f2bf(acc[fm][fn][r] * ivr[r]);
      }
    }
  }
}

// ---------------------------------------------------------------- launch
extern "C" void kernel_launch(void* const* d_in, const int* in_sizes, int n_in,
                              void* d_out, int out_size, void* d_ws, size_t ws_size,
                              hipStream_t stream) {
  const float* x = (const float*)d_in[0];
  const float* Wq = (const float*)d_in[1];
  const float* Wk = (const float*)d_in[2];
  const float* Wv = (const float*)d_in[3];
  const float* Wo = (const float*)d_in[4];
  float* out = (float*)d_out;

  char* ws = (char*)d_ws;
  unsigned short* xb   = (unsigned short*)(ws);                    // 16 MB
  unsigned short* Wqkv = (unsigned short*)(ws + (16u << 20));      // 6 MB
  unsigned short* Wob  = (unsigned short*)(ws + (22u << 20));      // 2 MB
  unsigned short* Qb   = (unsigned short*)(ws + (24u << 20));      // 16 MB
  unsigned short* Kb   = (unsigned short*)(ws + (40u << 20));      // 16 MB
  unsigned short* Vtb  = (unsigned short*)(ws + (56u << 20));      // 16 MB (V^T)
  unsigned short* Cb   = (unsigned short*)(ws + (72u << 20));      // 16 MB

  cvt_kernel<<<dim3(8192), dim3(256), 0, stream>>>(x, xb, (BATCH * SEQ * D_MODEL) / 4);
  cvtw_kernel<<<dim3(4096), dim3(256), 0, stream>>>(Wq, Wk, Wv, Wo, Wqkv, Wob);

  gemm_bt<0><<<dim3(16, 64), dim3(256), 0, stream>>>(xb, Wqkv, Qb, Kb, nullptr, nullptr);
  gemm_bt<2><<<dim3(8, 64), dim3(256), 0, stream>>>(xb, Wqkv, nullptr, nullptr, Vtb, nullptr);
  attn_fwd<<<dim3(64, 16), dim3(256), 0, stream>>>(Qb, Kb, Vtb, Cb);
  gemm_bt<1><<<dim3(8, 64), dim3(256), 0, stream>>>(Cb, Wob, nullptr, nullptr, nullptr, out);
}

// Round 4
// 185.218 us; speedup vs baseline: 1.0224x; 1.0224x over previous
//
#include <hip/hip_runtime.h>

#define D_MODEL 1024
#define SEQ 2048
#define BATCH 4
#define HEADS 16
#define HDIM 64

typedef short bf16x8 __attribute__((ext_vector_type(8)));
typedef float f32x4 __attribute__((ext_vector_type(4)));

#define FENCE() asm volatile("" ::: "memory")

__device__ __forceinline__ unsigned short f2bf(float f) {
  union { float f; unsigned int u; } c; c.f = f;
  unsigned int u = c.u;
  unsigned int r = (u + 0x7FFFu + ((u >> 16) & 1u)) >> 16;
  return (unsigned short)r;
}

__device__ __forceinline__ unsigned int cvt_pk_bf16(float a, float b) {
  unsigned int r;
  asm("v_cvt_pk_bf16_f32 %0, %1, %2" : "=v"(r) : "v"(a), "v"(b));
  return r;
}

__device__ __forceinline__ void async16(const void* g, const void* lds) {
  __builtin_amdgcn_global_load_lds((const __attribute__((address_space(1))) void*)g,
                                   (__attribute__((address_space(3))) void*)lds, 16, 0, 0);
}

// ---------------------------------------------------------------- converts
__global__ void cvt_kernel(const float* __restrict__ src,
                           unsigned short* __restrict__ dst, int n4) {
  int i = blockIdx.x * 256 + threadIdx.x;
  if (i >= n4) return;
  float4 v = ((const float4*)src)[i];
  ushort4 o;
  o.x = f2bf(v.x); o.y = f2bf(v.y); o.z = f2bf(v.z); o.w = f2bf(v.w);
  ((ushort4*)dst)[i] = o;
}

__global__ void cvtw_kernel(const float* __restrict__ Wq, const float* __restrict__ Wk,
                            const float* __restrict__ Wv, const float* __restrict__ Wo,
                            unsigned short* __restrict__ Wqkv,
                            unsigned short* __restrict__ Wob) {
  int b = blockIdx.x >> 10;   // 0..3
  int i = (blockIdx.x & 1023) * 256 + threadIdx.x;
  const float* s = (b == 0) ? Wq : (b == 1) ? Wk : (b == 2) ? Wv : Wo;
  unsigned short* d = (b == 3) ? Wob : (Wqkv + b * (D_MODEL * D_MODEL));
  float4 v = ((const float4*)s)[i];
  ushort4 o;
  o.x = f2bf(v.x); o.y = f2bf(v.y); o.z = f2bf(v.z); o.w = f2bf(v.w);
  ((ushort4*)d)[i] = o;
}

// ---------------------------------------------------------------- 256x256 8-phase GEMM
// C = A * Bw^T.  A: [M][1024] bf16, Bw: [rows][1024] bf16.
// 8 waves (2M x 4N), per-wave 128x64 (acc[8][4]), BK=64, 2x dbuf LDS (128 KiB),
// XOR-swizzled tiles (byte ^= (row&7)<<4) staged via pre-swizzled global sources,
// 4 phases/K-tile, counted vmcnt(4)/vmcnt(2), dual barriers, setprio on MFMA.
// MODE 0: N tiles in [0,2048) -> scatter Q/K [B*H][S][Dh] bf16
// MODE 1: N=1024 (Wo) -> fp32 out [M][1024]
// MODE 2: N tiles in [2048,3072) (Wv) -> swapped MFMA, scatter V^T [B*H][Dh][S]
template <int MODE>
__global__ __launch_bounds__(512, 2) void gemm256(
    const unsigned short* __restrict__ A, const unsigned short* __restrict__ Bw,
    unsigned short* __restrict__ Qd, unsigned short* __restrict__ Kd,
    unsigned short* __restrict__ Vtd, float* __restrict__ Od) {
  __shared__ unsigned short At[2][256 * 64];
  __shared__ unsigned short Bt[2][256 * 64];
  const int t = threadIdx.x;
  const int lane = t & 63;
  const int wid = t >> 6;
  const int wm = wid >> 2;   // 0..1
  const int wn = wid & 3;    // 0..3

  // bijective XCD swizzle (nwg % 8 == 0 for all grids here)
  const int gx = gridDim.x;
  const int nwg = gridDim.x * gridDim.y;
  int flat = blockIdx.y * gx + blockIdx.x;
  flat = (flat & 7) * (nwg >> 3) + (flat >> 3);
  const int m0 = (flat / gx) * 256;
  const int n0 = (MODE == 2 ? 2048 : 0) + (flat % gx) * 256;

  const int K = 1024;
  f32x4 acc[8][4] = {};

  // staging source (pre-swizzled column so linear LDS dest holds swizzled layout)
  const int srow = t >> 3;                       // 0..63
  const int scol = ((t & 7) ^ (srow & 7)) << 3;  // element col within 64
  const unsigned short* Ags = A + (size_t)(m0 + srow) * K + scol;
  const unsigned short* Bgs = Bw + (size_t)(n0 + srow) * K + scol;

  const int l15 = lane & 15;
  const int lh = lane >> 4;
  const int rsw = (l15 & 7) << 4;           // read-side XOR (bytes)
  const int cb0 = (lh * 16) ^ rsw;          // ks=0 col byte
  const int cb1 = (64 + lh * 16) ^ rsw;     // ks=1 col byte
  const int aBase = (wm * 128 + l15) * 128; // byte base (128B rows)
  const int bBase = (wn * 64 + l15) * 128;

#define STG_A(o, c, kn) async16(Ags + (size_t)(c) * 64 * K + (kn), &At[o][(c) * 4096 + t * 8])
#define STG_B(o, c, kn) async16(Bgs + (size_t)(c) * 64 * K + (kn), &Bt[o][(c) * 4096 + t * 8])

  // prologue: stage K-tile 0 fully
  STG_B(0, 0, 0); STG_B(0, 1, 0); STG_B(0, 2, 0); STG_B(0, 3, 0);
  STG_A(0, 0, 0); STG_A(0, 1, 0); STG_A(0, 2, 0); STG_A(0, 3, 0);
  asm volatile("s_waitcnt vmcnt(0)" ::: "memory");
  __builtin_amdgcn_s_barrier();
  FENCE();

  for (int kt = 0; kt < K; kt += 64) {
    const int s = (kt >> 6) & 1;
    const int o = s ^ 1;
    const int kn = kt + 64;
    const bool more = kn < K;
    const char* Ab = (const char*)&At[s][0];
    const char* Bb = (const char*)&Bt[s][0];

    bf16x8 bfr[4][2];
#pragma unroll
    for (int p = 0; p < 4; ++p) {
      // ds-reads for this phase's A quadrant (frags 2p, 2p+1)
      bf16x8 af[2][2];
#pragma unroll
      for (int i = 0; i < 2; ++i) {
        af[i][0] = *(const bf16x8*)(Ab + aBase + (2 * p + i) * 2048 + cb0);
        af[i][1] = *(const bf16x8*)(Ab + aBase + (2 * p + i) * 2048 + cb1);
      }
      if (p == 0) {
#pragma unroll
        for (int fn = 0; fn < 4; ++fn) {
          bfr[fn][0] = *(const bf16x8*)(Bb + bBase + fn * 2048 + cb0);
          bfr[fn][1] = *(const bf16x8*)(Bb + bBase + fn * 2048 + cb1);
        }
        if (more) { STG_B(o, 0, kn); STG_B(o, 1, kn); }
      } else if (p == 1) {
        if (more) { STG_B(o, 2, kn); STG_B(o, 3, kn); }
      } else if (p == 2) {
        if (more) { STG_A(o, 0, kn); STG_A(o, 2, kn); }
      } else {
        if (more) { STG_A(o, 1, kn); STG_A(o, 3, kn); }
      }
      __builtin_amdgcn_s_barrier();
      FENCE();
      __builtin_amdgcn_s_setprio(1);
#pragma unroll
      for (int ks = 0; ks < 2; ++ks)
#pragma unroll
        for (int i = 0; i < 2; ++i)
#pragma unroll
          for (int fn = 0; fn < 4; ++fn) {
            if (MODE == 2)
              acc[2 * p + i][fn] = __builtin_amdgcn_mfma_f32_16x16x32_bf16(
                  bfr[fn][ks], af[i][ks], acc[2 * p + i][fn], 0, 0, 0);
            else
              acc[2 * p + i][fn] = __builtin_amdgcn_mfma_f32_16x16x32_bf16(
                  af[i][ks], bfr[fn][ks], acc[2 * p + i][fn], 0, 0, 0);
          }
      __builtin_amdgcn_s_setprio(0);
      FENCE();
      if (p == 1) {
        if (more) asm volatile("s_waitcnt vmcnt(4)" ::: "memory");
        else      asm volatile("s_waitcnt vmcnt(0)" ::: "memory");
      } else if (p == 3) {
        if (more) asm volatile("s_waitcnt vmcnt(2)" ::: "memory");
        else      asm volatile("s_waitcnt vmcnt(0)" ::: "memory");
      }
      __builtin_amdgcn_s_barrier();
      FENCE();
    }
  }
#undef STG_A
#undef STG_B

  // epilogue
#pragma unroll
  for (int fm = 0; fm < 8; ++fm) {
#pragma unroll
    for (int fn = 0; fn < 4; ++fn) {
#pragma unroll
      for (int r = 0; r < 4; ++r) {
        float v = acc[fm][fn][r];
        if (MODE == 2) {
          int n = n0 + wn * 64 + fn * 16 + lh * 4 + r;
          int m = m0 + wm * 128 + fm * 16 + l15;
          int h = (n >> 6) & 15;
          int d = n & 63;
          int b = m >> 11;
          int s = m & 2047;
          Vtd[(((size_t)(b * HEADS + h)) * HDIM + d) * SEQ + s] = f2bf(v);
        } else {
          int m = m0 + wm * 128 + fm * 16 + lh * 4 + r;
          int n = n0 + wn * 64 + fn * 16 + l15;
          if (MODE == 0) {
            int p = n >> 10;  // 0=Q, 1=K
            int h = (n >> 6) & 15;
            int dh = n & 63;
            int b = m >> 11;
            int sx = m & 2047;
            unsigned short* dst = (p == 0) ? Qd : Kd;
            dst[(((size_t)(b * HEADS + h)) * SEQ + sx) * HDIM + dh] = f2bf(v);
          } else {
            Od[(size_t)m * D_MODEL + n] = v;
          }
        }
      }
    }
  }
}

// ---------------------------------------------------------------- flash attention (causal)
// (round-2 version, verbatim: 79 us known-good)
__global__ __launch_bounds__(256, 3) void attn_fwd(
    const unsigned short* __restrict__ Qg, const unsigned short* __restrict__ Kg,
    const unsigned short* __restrict__ Vtg, unsigned short* __restrict__ Cg) {
  __shared__ unsigned short Kl[64 * 64];      // [key][dh], rows XOR-swizzled
  __shared__ unsigned short Vl[64 * 64];      // [dh][key], rows XOR-swizzled
  __shared__ unsigned short Pl[4][32 * 72];   // per-wave P [q][key] +8 pad
  char* KlB = (char*)Kl;
  char* VlB = (char*)Vl;

  const int t = threadIdx.x;
  const int lane = t & 63;
  const int wq = t >> 6;
  const int bh = blockIdx.x;
  const int q0 = (15 - blockIdx.y) * 128;  // heavy blocks first
  const size_t base = (size_t)bh * SEQ * HDIM;
  const unsigned short* Qb = Qg + base;
  const unsigned short* Kb = Kg + base;
  const unsigned short* Vb = Vtg + base;  // [Dh][S]
  char* PlB = (char*)&Pl[wq][0];

  const int l15 = lane & 15;
  const int lh = lane >> 4;  // 0..3
  const int qrow = q0 + wq * 32;

  bf16x8 qf[2][2];
#pragma unroll
  for (int fm = 0; fm < 2; ++fm)
#pragma unroll
    for (int ks = 0; ks < 2; ++ks)
      qf[fm][ks] = *(const bf16x8*)&Qb[(size_t)(qrow + fm * 16 + l15) * HDIM +
                                       ks * 32 + lh * 8];

  f32x4 acc[2][4] = {};
  float mrun[2] = {-1e30f, -1e30f};
  float lrun[2] = {0.f, 0.f};

  const int srow = t >> 3;                         // 0..31
  const int sc8 = ((t & 7) ^ (srow & 7)) << 3;     // element offset within row

  const int kv_end = q0 + 128;
  for (int kv0 = 0; kv0 < kv_end; kv0 += 64) {
    __syncthreads();
    async16(Kb + (size_t)(kv0 + srow) * HDIM + sc8, &Kl[t * 8]);
    async16(Kb + (size_t)(kv0 + 32 + srow) * HDIM + sc8, &Kl[2048 + t * 8]);
    async16(Vb + (size_t)srow * SEQ + kv0 + sc8, &Vl[t * 8]);
    async16(Vb + (size_t)(32 + srow) * SEQ + kv0 + sc8, &Vl[2048 + t * 8]);
    asm volatile("s_waitcnt vmcnt(0)" ::: "memory");
    __syncthreads();

    if (kv0 <= qrow + 31) {
      // ---- S^T = K Q^T : C[key][q], lane holds 16 keys for q = l15
      f32x4 sfr[2][4] = {};
#pragma unroll
      for (int ks = 0; ks < 2; ++ks) {
        bf16x8 kf[4];
#pragma unroll
        for (int fn = 0; fn < 4; ++fn) {
          int row = fn * 16 + l15;
          kf[fn] = *(const bf16x8*)&KlB[row * 128 +
                                        ((ks * 64 + lh * 16) ^ ((row & 7) << 4))];
        }
#pragma unroll
        for (int fm = 0; fm < 2; ++fm)
#pragma unroll
          for (int fn = 0; fn < 4; ++fn)
            sfr[fm][fn] = __builtin_amdgcn_mfma_f32_16x16x32_bf16(
                kf[fn], qf[fm][ks], sfr[fm][fn], 0, 0, 0);
      }

      const bool need_mask = (kv0 + 63) > qrow;
#pragma unroll
      for (int fm = 0; fm < 2; ++fm) {
        const int q = qrow + fm * 16 + l15;
        float p[4][4];
        float mt = -1e30f;
#pragma unroll
        for (int fn = 0; fn < 4; ++fn)
#pragma unroll
          for (int r = 0; r < 4; ++r) {
            float v = sfr[fm][fn][r] * 0.125f;
            if (need_mask) {
              int key = kv0 + fn * 16 + lh * 4 + r;
              v = (key <= q) ? v : -1e30f;
            }
            p[fn][r] = v;
            mt = fmaxf(mt, v);
          }
        mt = fmaxf(mt, __shfl_xor(mt, 16));
        mt = fmaxf(mt, __shfl_xor(mt, 32));
        float mnew = fmaxf(mrun[fm], mt);
        float c = __expf(mrun[fm] - mnew);
        mrun[fm] = mnew;
        float st = 0.f;
#pragma unroll
        for (int fn = 0; fn < 4; ++fn)
#pragma unroll
          for (int r = 0; r < 4; ++r) {
            p[fn][r] = __expf(p[fn][r] - mnew);
            st += p[fn][r];
          }
        st += __shfl_xor(st, 16);
        st += __shfl_xor(st, 32);
        lrun[fm] = lrun[fm] * c + st;

#pragma unroll
        for (int fn = 0; fn < 4; ++fn) {
#pragma unroll
          for (int w = 0; w < 2; ++w) {
            unsigned int pk = cvt_pk_bf16(p[fn][2 * w], p[fn][2 * w + 1]);
            *(unsigned int*)&PlB[(fm * 16 + l15) * 144 + fn * 32 + lh * 8 + w * 4] = pk;
          }
        }
        float cr[4];
#pragma unroll
        for (int r = 0; r < 4; ++r) cr[r] = __shfl(c, lh * 4 + r);
#pragma unroll
        for (int fn = 0; fn < 4; ++fn)
#pragma unroll
          for (int r = 0; r < 4; ++r) acc[fm][fn][r] *= cr[r];
      }

      // ---- ctx += P V
#pragma unroll
      for (int ks = 0; ks < 2; ++ks) {
        bf16x8 pf[2], vf[4];
#pragma unroll
        for (int fm = 0; fm < 2; ++fm)
          pf[fm] = *(const bf16x8*)&PlB[(fm * 16 + l15) * 144 + ks * 64 + lh * 16];
#pragma unroll
        for (int fn = 0; fn < 4; ++fn) {
          int row = fn * 16 + l15;
          vf[fn] = *(const bf16x8*)&VlB[row * 128 +
                                        ((ks * 64 + lh * 16) ^ ((row & 7) << 4))];
        }
#pragma unroll
        for (int fm = 0; fm < 2; ++fm)
#pragma unroll
          for (int fn = 0; fn < 4; ++fn)
            acc[fm][fn] = __builtin_amdgcn_mfma_f32_16x16x32_bf16(
                pf[fm], vf[fn], acc[fm][fn], 0, 0, 0);
      }
    }
  }

  const int b = bh >> 4;
  const int h = bh & 15;
#pragma unroll
  for (int fm = 0; fm < 2; ++fm) {
    float inv = 1.0f / lrun[fm];
    float ivr[4];
#pragma unroll
    for (int r = 0; r < 4; ++r) ivr[r] = __shfl(inv, lh * 4 + r);
#pragma unroll
    for (int r = 0; r < 4; ++r) {
      int s = qrow + fm * 16 + lh * 4 + r;
#pragma unroll
      for (int fn = 0; fn < 4; ++fn) {
        int dh = fn * 16 + l15;
        Cg[((size_t)(b * SEQ + s)) * D_MODEL + h * HDIM + dh] =
            f2bf(acc[fm][fn][r] * ivr[r]);
      }
    }
  }
}

// ---------------------------------------------------------------- launch
extern "C" void kernel_launch(void* const* d_in, const int* in_sizes, int n_in,
                              void* d_out, int out_size, void* d_ws, size_t ws_size,
                              hipStream_t stream) {
  const float* x = (const float*)d_in[0];
  const float* Wq = (const float*)d_in[1];
  const float* Wk = (const float*)d_in[2];
  const float* Wv = (const float*)d_in[3];
  const float* Wo = (const float*)d_in[4];
  float* out = (float*)d_out;

  char* ws = (char*)d_ws;
  unsigned short* xb   = (unsigned short*)(ws);                    // 16 MB
  unsigned short* Wqkv = (unsigned short*)(ws + (16u << 20));      // 6 MB
  unsigned short* Wob  = (unsigned short*)(ws + (22u << 20));      // 2 MB
  unsigned short* Qb   = (unsigned short*)(ws + (24u << 20));      // 16 MB
  unsigned short* Kb   = (unsigned short*)(ws + (40u << 20));      // 16 MB
  unsigned short* Vtb  = (unsigned short*)(ws + (56u << 20));      // 16 MB (V^T)
  unsigned short* Cb   = (unsigned short*)(ws + (72u << 20));      // 16 MB

  cvt_kernel<<<dim3(8192), dim3(256), 0, stream>>>(x, xb, (BATCH * SEQ * D_MODEL) / 4);
  cvtw_kernel<<<dim3(4096), dim3(256), 0, stream>>>(Wq, Wk, Wv, Wo, Wqkv, Wob);

  gemm256<0><<<dim3(8, 32), dim3(512), 0, stream>>>(xb, Wqkv, Qb, Kb, nullptr, nullptr);
  gemm256<2><<<dim3(4, 32), dim3(512), 0, stream>>>(xb, Wqkv, nullptr, nullptr, Vtb, nullptr);
  attn_fwd<<<dim3(64, 16), dim3(256), 0, stream>>>(Qb, Kb, Vtb, Cb);
  gemm256<1><<<dim3(4, 32), dim3(512), 0, stream>>>(Cb, Wob, nullptr, nullptr, nullptr, out);
}